// Round 13
// baseline (250.110 us; speedup 1.0000x reference)
//
#include <hip/hip_runtime.h>
#include <hip/hip_bf16.h>
#include <cstdint>
#include <cstddef>

// ButterflyLayer2D on MI355X.
// Round theme: fused12 v7 — make B-fragment reuse structural. Five rounds
// of evidence: the compiler never keeps the 128-VGPR weight arrays resident
// (VGPR stuck at ~100), so each MFMA re-loads its B operand: 128 B-loads/
// wave/phase -> ~512 KB/block of L2 weight traffic -> the stable 57 us gap
// above the 13.7 us MFMA floor. v7 interchanges the loops (pos innermost):
// per (cd/ab,ks): 4 A-loads, then per fn ONE B-load feeding 4 MFMAs
// (acc[pos][fn]). Operand loads 128B+32A -> 32B+32A per 128 MFMA, short
// live ranges the compiler must honor. Accumulation order per acc element
// unchanged (cd0ks0,cd0ks1,cd1ks0,... / ab0ks0,...) -> bit-identical.
// prep0/stage0/lvl3/f456/launch = round-12 verbatim.

typedef __attribute__((ext_vector_type(8))) short short8;
typedef __attribute__((ext_vector_type(4))) float f32x4;
typedef unsigned short ushort_t;

static __device__ __forceinline__ float b2f(const __hip_bfloat16 x) {
    return __bfloat162float(x);
}
static __device__ __forceinline__ ushort_t f2bf(float x) {
    __hip_bfloat16 h = __float2bfloat16(x);
    ushort_t u;
    __builtin_memcpy(&u, &h, 2);
    return u;
}
static __device__ __forceinline__ void gl_lds16(const void* g, void* l) {
    __builtin_amdgcn_global_load_lds(
        (const __attribute__((address_space(1))) void*)g,
        (__attribute__((address_space(3))) void*)l, 16, 0, 0);
}
// gfx9 waitcnt encodings: lgkmcnt(0) only / vmcnt(0) only
#define WAIT_LGKM0() __builtin_amdgcn_s_waitcnt(0xC07F)
#define WAIT_VM0()   __builtin_amdgcn_s_waitcnt(0x0F70)

#define PREP_BLOCKS 2533

// ---------------------------------------------------------------------------
// prep work. gid ranges: [0,565248) level weights; [565248,630784) Wd;
// [630784,648448) bias.
// ---------------------------------------------------------------------------
static __device__ __forceinline__ void prep_work(
    int gid, int isbf,
    const void* f1, const void* f2, const void* f3,
    const void* f4, const void* f5, const void* f6, const void* wdsrc,
    const void* b1, const void* b2, const void* b3,
    const void* b4, const void* b5, const void* b6,
    ushort_t* __restrict__ wbuf, ushort_t* __restrict__ wdbuf,
    float* __restrict__ bbuf)
{
    if (gid >= 648448) return;
    if (gid >= 630784) {
        const int bg = gid - 630784;
        const void* src; int base;
        if      (bg <   256) { src = b1; base = 0;     }
        else if (bg <  1280) { src = b2; base = 256;   }
        else if (bg <  5376) { src = b3; base = 1280;  }
        else if (bg <  9472) { src = b4; base = 5376;  }
        else if (bg < 13568) { src = b5; base = 9472;  }
        else                 { src = b6; base = 13568; }
        const int local = bg - base;
        bbuf[bg] = isbf ? b2f(((const __hip_bfloat16*)src)[local])
                        : ((const float*)src)[local];
        return;
    }
    if (gid >= 565248) {
        const int local = gid - 565248;
        const int lane = local & 63;
        const int slot = (local >> 6) & 15;
        const int site = local >> 10;
        const int ks2 = slot >> 3, nh = slot & 7, q = lane >> 4;
        const int n = nh * 16 + (lane & 15);
        const int r = n >> 6, kk = n & 63;
        const int cbase = ks2 * 32 + q * 8;
        ushort_t pk[8];
        if (isbf) {
            const ushort_t* s = (const ushort_t*)wdsrc;
            #pragma unroll
            for (int j = 0; j < 8; j++)
                pk[j] = s[(((size_t)(site * 2 + r) * 64 + cbase + j) * 64) + kk];
        } else {
            const float* s = (const float*)wdsrc;
            #pragma unroll
            for (int j = 0; j < 8; j++)
                pk[j] = f2bf(s[(((size_t)(site * 2 + r) * 64 + cbase + j) * 64) + kk]);
        }
        *(uint4*)&wdbuf[(size_t)local * 8] = *(uint4*)pk;
        return;
    }
    const void* fsrc; int base;
    if      (gid <   8192) { fsrc = f1; base = 0;      }
    else if (gid <  40960) { fsrc = f2; base = 8192;   }
    else if (gid < 172032) { fsrc = f3; base = 40960;  }
    else if (gid < 303104) { fsrc = f4; base = 172032; }
    else if (gid < 434176) { fsrc = f5; base = 303104; }
    else                   { fsrc = f6; base = 434176; }
    const int local = gid - base;
    const int lane = local & 63;
    const int slot = (local >> 6) & 7;
    const int sitetap = local >> 9;
    const int ks = slot >> 2, nh = slot & 3, q = lane >> 4;
    const int n = (lane & 15) + nh * 16;
    const int kbase = ks * 32 + q * 8;
    ushort_t pk[8];
    if (isbf) {
        const ushort_t* s = (const ushort_t*)fsrc + (size_t)sitetap * 4096;
        #pragma unroll
        for (int j = 0; j < 8; j++) pk[j] = s[(kbase + j) * 64 + n];
    } else {
        const float* s = (const float*)fsrc + (size_t)sitetap * 4096;
        #pragma unroll
        for (int j = 0; j < 8; j++) pk[j] = f2bf(s[(kbase + j) * 64 + n]);
    }
    *(uint4*)&wbuf[(size_t)gid * 8] = *(uint4*)pk;
}

// ---------------------------------------------------------------------------
// Stage 0 body: patch-embed, register-tiled, bf16 out.
// Output x0 layout: (h=X, w, b, c) with batch stride Bc (site 0 implicit).
// ---------------------------------------------------------------------------
static __device__ __forceinline__ void stage0_body(
    int blk, int isbf,
    const void* __restrict__ in_data, const void* __restrict__ filt,
    const void* __restrict__ bias, __hip_bfloat16* __restrict__ x0,
    int b_off, int Bc)
{
    const int X  = blk & 63;
    const int bl = blk >> 6;
    const int bg = bl + b_off;

    __shared__ float sIn[4][256];
    __shared__ float sF[16][64];
    __shared__ float sB[64];

    const int t = threadIdx.x;
    const size_t srow = ((size_t)bg * 256 + (size_t)X * 4) * 256;

    if (isbf) {
        const __hip_bfloat16* src = (const __hip_bfloat16*)in_data + srow;
        #pragma unroll
        for (int i = 0; i < 4; i++) {
            int flat = i * 256 + t;
            int p = flat >> 8, col = flat & 255;
            sIn[p][col] = b2f(src[(size_t)p * 256 + col]);
        }
        const __hip_bfloat16* fsrc = (const __hip_bfloat16*)filt;
        #pragma unroll
        for (int i = 0; i < 4; i++) {
            int flat = i * 256 + t;
            sF[flat >> 6][flat & 63] = b2f(fsrc[flat]);
        }
        if (t < 64) sB[t] = b2f(((const __hip_bfloat16*)bias)[t]);
    } else {
        const float* src = (const float*)in_data + srow;
        const int p = t >> 6, c4 = (t & 63) * 4;
        *(float4*)&sIn[p][c4] = *(const float4*)(src + (size_t)p * 256 + c4);
        const float* fsrc = (const float*)filt;
        #pragma unroll
        for (int i = 0; i < 4; i++) {
            int flat = i * 256 + t;
            sF[flat >> 6][flat & 63] = fsrc[flat];
        }
        if (t < 64) sB[t] = ((const float*)bias)[t];
    }
    __syncthreads();

    const int ty = t >> 4;
    const int tc = t & 15;

    float acc[4][4];
    {
        const float4 bv = *(const float4*)&sB[tc * 4];
        #pragma unroll
        for (int yi = 0; yi < 4; yi++) {
            acc[yi][0] = bv.x; acc[yi][1] = bv.y;
            acc[yi][2] = bv.z; acc[yi][3] = bv.w;
        }
    }

    #pragma unroll
    for (int p = 0; p < 4; p++) {
        float4 rin[4], rf[4];
        #pragma unroll
        for (int yi = 0; yi < 4; yi++)
            rin[yi] = *(const float4*)&sIn[p][ty * 16 + yi * 4];
        #pragma unroll
        for (int q = 0; q < 4; q++)
            rf[q] = *(const float4*)&sF[p * 4 + q][tc * 4];
        #pragma unroll
        for (int yi = 0; yi < 4; yi++) {
            #pragma unroll
            for (int q = 0; q < 4; q++) {
                const float a = ((const float*)&rin[yi])[q];
                acc[yi][0] = fmaf(a, rf[q].x, acc[yi][0]);
                acc[yi][1] = fmaf(a, rf[q].y, acc[yi][1]);
                acc[yi][2] = fmaf(a, rf[q].z, acc[yi][2]);
                acc[yi][3] = fmaf(a, rf[q].w, acc[yi][3]);
            }
        }
    }

    // store to (h=X, w, b, c): contiguous 64 B per (w, tc-group)
    ushort_t* dst = (ushort_t*)x0;
    #pragma unroll
    for (int yi = 0; yi < 4; yi++) {
        uint2 pk;
        pk.x = (uint32_t)f2bf(fmaxf(acc[yi][0], 0.f))
             | ((uint32_t)f2bf(fmaxf(acc[yi][1], 0.f)) << 16);
        pk.y = (uint32_t)f2bf(fmaxf(acc[yi][2], 0.f))
             | ((uint32_t)f2bf(fmaxf(acc[yi][3], 0.f)) << 16);
        const int wpos = ty * 4 + yi;
        *(uint2*)(dst + ((size_t)(X * 64 + wpos) * Bc + bl) * 64 + tc * 4) = pk;
    }
}

// ---------------------------------------------------------------------------
// Merged prep + stage0. Grid = PREP_BLOCKS + Bc*64.
// ---------------------------------------------------------------------------
__global__ __launch_bounds__(256) void k_prep0(
    const void* __restrict__ in_data,
    const void* f1, const void* f2, const void* f3,
    const void* f4, const void* f5, const void* f6, const void* wdsrc,
    const void* b1, const void* b2, const void* b3,
    const void* b4, const void* b5, const void* b6,
    ushort_t* __restrict__ wbuf, ushort_t* __restrict__ wdbuf,
    float* __restrict__ bbuf, int* __restrict__ flag,
    const void* __restrict__ filt, const void* __restrict__ bias0,
    __hip_bfloat16* __restrict__ x0, int Bc)
{
    __shared__ int sflag;
    const int t = threadIdx.x;
    if (t < 64) {
        const float v = __uint_as_float(((const uint32_t*)in_data)[t]);
        const bool plaus = (v == 0.0f) || (fabsf(v) > 1e-8f && fabsf(v) < 1e4f);
        const unsigned long long m = __ballot(plaus);
        if (t == 0) sflag = (__popcll(m) >= 48) ? 0 : 1;
    }
    __syncthreads();
    const int isbf = sflag;

    if (blockIdx.x < PREP_BLOCKS) {
        if (blockIdx.x == 0 && t == 0) *flag = isbf;
        prep_work(blockIdx.x * 256 + t, isbf,
                  f1, f2, f3, f4, f5, f6, wdsrc,
                  b1, b2, b3, b4, b5, b6, wbuf, wdbuf, bbuf);
    } else {
        stage0_body(blockIdx.x - PREP_BLOCKS, isbf, in_data, filt, bias0, x0, 0, Bc);
    }
}

__global__ __launch_bounds__(256) void k_stage0(
    const void* __restrict__ in_data, const void* __restrict__ filt,
    const void* __restrict__ bias, __hip_bfloat16* __restrict__ x0,
    const int* __restrict__ flag, int b_off, int Bc)
{
    stage0_body(blockIdx.x, *flag, in_data, filt, bias, x0, b_off, Bc);
}

// ---------------------------------------------------------------------------
// k_fused12 v7: fused levels 1+2, parent-split, pos-innermost MFMA loops.
// Block = (h2 in 16, w2-strip in 4, parent (i,j) in 4, mt16). Grid 256*mt.
// LDS: l1b [0,18432) 16 slices x 16 rows x 72; so_buf [18432,+8704).
// 54272 B, launch_bounds(256,2). 1 barrier.
// Phase A: per (cd,ks): 4 direct global A-loads (one per position), then per
//   fn ONE w1 B-load feeding 4 MFMAs into acc[pos][fn]. 32 B + 32 A loads
//   per 128 MFMA (was 128 B + 32 A).
// Phase B: same structure over (ab,ks) with A from l1b LDS and B from w2.
// ---------------------------------------------------------------------------
__global__ __launch_bounds__(256, 2) void k_fused12(
    const __hip_bfloat16* __restrict__ xin,   // L0: (64,64,Bc,64) pos-major
    const ushort_t* __restrict__ w1,          // lvl1 B-frags (4 sites)
    const ushort_t* __restrict__ w2,          // lvl2 B-frags (16 sites)
    const float* __restrict__ b1, const float* __restrict__ b2,
    __hip_bfloat16* __restrict__ xout,        // L2 out: (16,16,16,Bc,64)
    int Bc, int mtiles)
{
    __shared__ __align__(16) ushort_t smem[27136];  // l1b 18432 + so_buf 8704

    int idx = blockIdx.x;
    const int mt = idx % mtiles; idx /= mtiles;
    const int parent = idx & 3; idx >>= 2;
    const int wstrip = idx & 3;
    const int h2p = idx >> 2;
    const int ip = parent >> 1, jp = parent & 1;

    const int t = threadIdx.x;
    const int wave = t >> 6, lane = t & 63;
    const int lm = lane & 15, lq = lane >> 4;

    const size_t pstride = (size_t)Bc * 64;

    int brow = mt * 16 + lm;
    if (brow >= Bc) brow = Bc - 1;

    const ushort_t* w1site = w1 + (size_t)parent * 16384 + lane * 8;

    float bv1[4];
    #pragma unroll
    for (int fn = 0; fn < 4; fn++) bv1[fn] = b1[parent * 64 + fn * 16 + lm];

    const f32x4 zero = {0.f, 0.f, 0.f, 0.f};
    ushort_t* l1b = smem;                    // 16 slices x 1152
    const int wa = wave >> 1, wb = wave & 1; // phase-A ab position

    // ---------------- phase A: pos-innermost, barrier-free ----------------
    {
        f32x4 acc[4][4];   // [pos][fn]
        #pragma unroll
        for (int p = 0; p < 4; p++)
            #pragma unroll
            for (int fn = 0; fn < 4; fn++) acc[p][fn] = zero;

        #pragma unroll
        for (int cd = 0; cd < 4; cd++) {
            const int hi0 = 4 * h2p + 2 * wa + (cd >> 1);
            const int wbase = 2 * wb + (cd & 1);
            #pragma unroll
            for (int ks = 0; ks < 2; ks++) {
                short8 afr[4];
                #pragma unroll
                for (int pos = 0; pos < 4; pos++) {
                    const int wi0 = 4 * (wstrip * 4 + pos) + wbase;
                    afr[pos] = *(const short8*)(
                        xin + ((size_t)hi0 * 64 + wi0) * pstride
                            + (size_t)brow * 64 + ks * 32 + lq * 8);
                }
                #pragma unroll
                for (int fn = 0; fn < 4; fn++) {
                    short8 bfr = *(const short8*)(w1site + (cd * 8 + ks * 4 + fn) * 512);
                    #pragma unroll
                    for (int pos = 0; pos < 4; pos++)
                        acc[pos][fn] = __builtin_amdgcn_mfma_f32_16x16x32_bf16(
                            afr[pos], bfr, acc[pos][fn], 0, 0, 0);
                }
            }
        }
        // epilogue -> L1 slices (pos*4 + wave), bias1 + relu
        #pragma unroll
        for (int pos = 0; pos < 4; pos++) {
            ushort_t* dst = l1b + (pos * 4 + wave) * 1152;
            #pragma unroll
            for (int fn = 0; fn < 4; fn++) {
                #pragma unroll
                for (int r = 0; r < 4; r++) {
                    const int m = lq * 4 + r;
                    dst[m * 72 + fn * 16 + lm] =
                        f2bf(fmaxf(acc[pos][fn][r] + bv1[fn], 0.f));
                }
            }
        }
    }
    __syncthreads();   // the ONLY barrier: all L1 slices visible cross-wave

    // ---------------- phase B: wave = child site, pos-innermost -----------
    {
        const int di = wave >> 1, dj = wave & 1;
        const int s2 = (2 * ip + di) * 4 + (2 * jp + dj);
        const ushort_t* w2site = w2 + (size_t)s2 * 16384 + lane * 8;

        float bv2[4];
        #pragma unroll
        for (int fn = 0; fn < 4; fn++) bv2[fn] = b2[s2 * 64 + fn * 16 + lm];

        f32x4 acc[4][4];   // [pos][fn]
        #pragma unroll
        for (int p = 0; p < 4; p++)
            #pragma unroll
            for (int fn = 0; fn < 4; fn++) acc[p][fn] = zero;

        #pragma unroll
        for (int ab = 0; ab < 4; ab++) {
            #pragma unroll
            for (int ks = 0; ks < 2; ks++) {
                short8 afr[4];
                #pragma unroll
                for (int pos = 0; pos < 4; pos++) {
                    const ushort_t* sl = l1b + (pos * 4 + ab) * 1152;
                    afr[pos] = *(const short8*)&sl[lm * 72 + ks * 32 + lq * 8];
                }
                #pragma unroll
                for (int fn = 0; fn < 4; fn++) {
                    short8 bfr = *(const short8*)(w2site + (ab * 8 + ks * 4 + fn) * 512);
                    #pragma unroll
                    for (int pos = 0; pos < 4; pos++)
                        acc[pos][fn] = __builtin_amdgcn_mfma_f32_16x16x32_bf16(
                            afr[pos], bfr, acc[pos][fn], 0, 0, 0);
                }
            }
        }

        // epilogue per position: LDS transpose + coalesced uint4 stores
        ushort_t* so_buf = smem + 18432 + wave * 2176;
        #pragma unroll
        for (int pos = 0; pos < 4; pos++) {
            const int w2p = wstrip * 4 + pos;
            #pragma unroll
            for (int fn = 0; fn < 4; fn++) {
                #pragma unroll
                for (int r = 0; r < 4; r++) {
                    const int m = lq * 4 + r;
                    so_buf[m * 68 + fn * 16 + lm] =
                        f2bf(fmaxf(acc[pos][fn][r] + bv2[fn], 0.f));
                }
            }
            const size_t obase = ((size_t)s2 * 256 + h2p * 16 + w2p) * pstride;
            #pragma unroll
            for (int i2 = 0; i2 < 2; i2++) {
                const int task = i2 * 64 + lane;
                const int oct = task & 7, row = task >> 3;
                const int brw = mt * 16 + row;
                if (brw < Bc) {
                    *(uint4*)(xout + obase + (size_t)brw * 64 + oct * 8) =
                        *(const uint4*)&so_buf[row * 68 + oct * 8];
                }
            }
        }
    }
}

// ---------------------------------------------------------------------------
// Repeat level (used for lvl3 only), round-12 verbatim.
// ---------------------------------------------------------------------------
__global__ __launch_bounds__(256, 2) void k_level4(
    const __hip_bfloat16* __restrict__ xin,
    const ushort_t* __restrict__ wbuf,
    const float* __restrict__ bbuf,
    __hip_bfloat16* __restrict__ xout,
    int Nv_out, int HW, int Bc, int mtiles)
{
    __shared__ __align__(16) ushort_t smem[17408];

    int idx = blockIdx.x;
    const int mt = idx % mtiles; idx /= mtiles;
    const int w  = idx % HW; idx /= HW;
    const int h  = idx % HW; idx /= HW;
    const int Nv_in = Nv_out >> 1;
    const int vp = idx % Nv_in;
    const int up = idx / Nv_in;

    const int t = threadIdx.x;
    const int wave = t >> 6, lane = t & 63;
    const int lm = lane & 15, lq = lane >> 4;

    const int so = (2 * up + (wave >> 1)) * Nv_out + (2 * vp + (wave & 1));
    const int H_in = HW * 2;
    const size_t pstride = (size_t)Bc * 64;
    const size_t siteb = (size_t)(up * Nv_in + vp) * H_in * H_in * pstride;
    const ushort_t* wsite = wbuf + (size_t)so * 4 * 4096 + lane * 8;

    {
        const int hi = 2 * h + (wave >> 1), wi = 2 * w + (wave & 1);
        const size_t tapoff = siteb + ((size_t)hi * H_in + wi) * pstride;
        #pragma unroll
        for (int j = 0; j < 8; j++) {
            const int ks = j >> 2, mh = j & 3;
            int b = mt * 64 + mh * 16 + lm;
            if (b >= Bc) b = Bc - 1;
            gl_lds16(xin + tapoff + (size_t)b * 64 + ks * 32 + lq * 8,
                     &smem[(wave * 8 + j) * 512]);
        }
    }

    short8 breg[32];
    #pragma unroll
    for (int s = 0; s < 32; s++)
        breg[s] = *(const short8*)(wsite + s * 512);
    __builtin_amdgcn_sched_barrier(0);

    float bv[4];
    #pragma unroll
    for (int fn = 0; fn < 4; fn++) bv[fn] = bbuf[so * 64 + fn * 16 + lm];

    __syncthreads();

    const f32x4 zero = {0.f, 0.f, 0.f, 0.f};
    f32x4 acc[4][4];
    #pragma unroll
    for (int i = 0; i < 4; i++)
        #pragma unroll
        for (int j = 0; j < 4; j++) acc[i][j] = zero;

    #pragma unroll
    for (int tap = 0; tap < 4; tap++) {
        #pragma unroll
        for (int ks = 0; ks < 2; ks++) {
            #pragma unroll
            for (int fm = 0; fm < 4; fm++) {
                short8 a = *(const short8*)&smem[(tap * 8 + ks * 4 + fm) * 512 + lane * 8];
                #pragma unroll
                for (int fn = 0; fn < 4; fn++)
                    acc[fm][fn] = __builtin_amdgcn_mfma_f32_16x16x32_bf16(
                        a, breg[tap * 8 + ks * 4 + fn], acc[fm][fn], 0, 0, 0);
            }
        }
    }
    __syncthreads();

    ushort_t* so_buf = smem + wave * 4352;
    #pragma unroll
    for (int fm = 0; fm < 4; fm++) {
        #pragma unroll
        for (int fn = 0; fn < 4; fn++) {
            #pragma unroll
            for (int r = 0; r < 4; r++) {
                const int row = fm * 16 + lq * 4 + r;
                so_buf[row * 68 + fn * 16 + lm] =
                    f2bf(fmaxf(acc[fm][fn][r] + bv[fn], 0.f));
            }
        }
    }
    __syncthreads();

    const size_t obase = ((size_t)so * HW * HW + (size_t)h * HW + w) * pstride;
    #pragma unroll
    for (int i = 0; i < 8; i++) {
        const int task = i * 64 + lane;
        const int oct = task & 7, row = task >> 3;
        const int b = mt * 64 + row;
        if (b < Bc) {
            *(uint4*)(xout + obase + (size_t)b * 64 + oct * 8) =
                *(const uint4*)&so_buf[row * 68 + oct * 8];
        }
    }
}

// ---------------------------------------------------------------------------
// k_f456: fused L4 + L5 + L6 + final (round-12 verbatim).
// ---------------------------------------------------------------------------
__global__ __launch_bounds__(256) void k_f456(
    const __hip_bfloat16* __restrict__ xin,   // L3 out: (64, 8,8, Bc, 64)
    const ushort_t* __restrict__ w4, const ushort_t* __restrict__ w5,
    const ushort_t* __restrict__ w6, const ushort_t* __restrict__ wd,
    const float* __restrict__ b4, const float* __restrict__ b5,
    const float* __restrict__ b6,
    void* __restrict__ out, const int* __restrict__ flag,
    int Bc, int b_off, int mtiles)
{
    const int isbf = *flag;
    const int bx = blockIdx.x;
    const int mt = bx % mtiles;
    const int site = bx / mtiles;
    const int u = site >> 3, v = site & 7;

    __shared__ __align__(16) ushort_t smem[37376];

    const int t = threadIdx.x;
    const int wv = t >> 6, lane = t & 63;
    const int lm = lane & 15, lq = lane >> 4;

    const ushort_t* w6s = w6 + (size_t)site * 16384 + lane * 8;
    const ushort_t* wds = wd + (size_t)site * 8192  + lane * 8;

    float bv4[4], bv5[4];
    #pragma unroll
    for (int fn = 0; fn < 4; fn++) {
        bv4[fn] = b4[site * 64 + fn * 16 + lm];
        bv5[fn] = b5[site * 64 + fn * 16 + lm];
    }
    const float bv6 = b6[site * 64 + wv * 16 + lm];

    {
        const ushort_t* w4s = w4 + (size_t)site * 16384;
        #pragma unroll
        for (int s2 = 0; s2 < 8; s2++) {
            const int s = wv * 8 + s2;
            gl_lds16(w4s + s * 512 + lane * 8, &smem[s * 512]);
        }
    }
    __syncthreads();

    const f32x4 zero = {0.f, 0.f, 0.f, 0.f};
    const int h5 = wv >> 1, w5p = wv & 1;
    ushort_t* mid1w = smem + 16384 + wv * 4224;
    ushort_t* Aw = smem + 33280 + wv * 1024;
    const size_t pstride = (size_t)Bc * 64;

    int brow = mt * 16 + lm;
    if (brow >= Bc) brow = Bc - 1;
    const __hip_bfloat16* xbase =
        xin + (size_t)site * 64 * pstride + (size_t)brow * 64 + lq * 8;

    for (int i = 0; i < 4; i++) {
        const int h4 = 2 * h5 + (i >> 1), w4p = 2 * w5p + (i & 1);
        f32x4 acc[4];
        #pragma unroll
        for (int b_ = 0; b_ < 4; b_++) acc[b_] = zero;

        for (int tap = 0; tap < 4; tap++) {
            const int h3 = 2 * h4 + (tap >> 1), w3 = 2 * w4p + (tap & 1);
            const size_t poff = (size_t)(h3 * 8 + w3) * pstride;
            WAIT_LGKM0();
            #pragma unroll
            for (int ks = 0; ks < 2; ks++) {
                gl_lds16(xbase + poff + ks * 32, &Aw[ks * 512]);
            }
            WAIT_VM0();
            __builtin_amdgcn_sched_barrier(0);
            #pragma unroll
            for (int ks = 0; ks < 2; ks++) {
                short8 a = *(const short8*)&Aw[ks * 512 + lane * 8];
                #pragma unroll
                for (int fn = 0; fn < 4; fn++) {
                    short8 bfr = *(const short8*)&smem[(tap * 8 + ks * 4 + fn) * 512 + lane * 8];
                    acc[fn] = __builtin_amdgcn_mfma_f32_16x16x32_bf16(a, bfr, acc[fn], 0, 0, 0);
                }
            }
        }
        #pragma unroll
        for (int fn = 0; fn < 4; fn++) {
            #pragma unroll
            for (int r = 0; r < 4; r++) {
                const int m = lq * 4 + r;
                const int ch = fn * 16 + lm;
                mid1w[m * 264 + i * 64 + ch] =
                    f2bf(fmaxf(acc[fn][r] + bv4[fn], 0.f));
            }
        }
    }
    __syncthreads();

    {
        const ushort_t* w5s = w5 + (size_t)site * 16384;
        #pragma unroll
        for (int s2 = 0; s2 < 8; s2++) {
            const int s = wv * 8 + s2;
            gl_lds16(w5s + s * 512 + lane * 8, &smem[s * 512]);
        }
    }
    __syncthreads();

    short8 b3r[8];
    short8 wdr[4];
    {
        f32x4 acc2[4];
        #pragma unroll
        for (int b_ = 0; b_ < 4; b_++) acc2[b_] = zero;

        #pragma unroll
        for (int i = 0; i < 4; i++) {
            #pragma unroll
            for (int ks = 0; ks < 2; ks++) {
                short8 a0 = *(const short8*)&mid1w[lm * 264 + i * 64 + ks * 32 + lq * 8];
                #pragma unroll
                for (int fn = 0; fn < 4; fn++) {
                    short8 bfr = *(const short8*)&smem[(i * 8 + ks * 4 + fn) * 512 + lane * 8];
                    acc2[fn] = __builtin_amdgcn_mfma_f32_16x16x32_bf16(a0, bfr, acc2[fn], 0, 0, 0);
                }
            }
        }

        #pragma unroll
        for (int tap = 0; tap < 4; tap++)
            #pragma unroll
            for (int ks = 0; ks < 2; ks++)
                b3r[tap * 2 + ks] = *(const short8*)(w6s + (tap * 8 + ks * 4 + wv) * 512);
        #pragma unroll
        for (int ks = 0; ks < 2; ks++)
            #pragma unroll
            for (int n2 = 0; n2 < 2; n2++)
                wdr[ks * 2 + n2] = *(const short8*)(wds + (ks * 8 + 2 * wv + n2) * 512);

        #pragma unroll
        for (int fn = 0; fn < 4; fn++) {
            #pragma unroll
            for (int r = 0; r < 4; r++) {
                const int m = lq * 4 + r;
                const int ch = fn * 16 + lm;
                mid1w[m * 72 + ch] =
                    f2bf(fmaxf(acc2[fn][r] + bv5[fn], 0.f));
            }
        }
    }
    __syncthreads();

    {
        f32x4 acc3 = zero;
        #pragma unroll
        for (int tap = 0; tap < 4; tap++) {
            const ushort_t* sl = smem + 16384 + tap * 4224;
            #pragma unroll
            for (int ks = 0; ks < 2; ks++) {
                short8 a0 = *(const short8*)&sl[lm * 72 + ks * 32 + lq * 8];
                acc3 = __builtin_amdgcn_mfma_f32_16x16x32_bf16(a0, b3r[tap * 2 + ks], acc3, 0, 0, 0);
            }
        }
        ushort_t* mid3 = smem + 33280;
        #pragma unroll
        for (int r = 0; r < 4; r++) {
            const int m = lq * 4 + r;
            const int ch = wv * 16 + lm;
            mid3[m * 72 + ch] = f2bf(fmaxf(acc3[r] + bv6, 0.f));
        }
    }
    __syncthreads();

    {
        const ushort_t* mid3 = smem + 33280;
        f32x4 acc4[2];
        acc4[0] = zero; acc4[1] = zero;
        #pragma unroll
        for (int ks = 0; ks < 2; ks++) {
            short8 a0 = *(const short8*)&mid3[lm * 72 + ks * 32 + lq * 8];
            #pragma unroll
            for (int n2 = 0; n2 < 2; n2++) {
                acc4[n2] = __builtin_amdgcn_mfma_f32_16x16x32_bf16(a0, wdr[ks * 2 + n2], acc4[n2], 0, 0, 0);
            }
        }
        #pragma unroll
        for (int n2 = 0; n2 < 2; n2++) {
            const int n = (2 * wv + n2) * 16 + lm;
            const int rr = n >> 6, ou = (n >> 3) & 7, ov = n & 7;
            const size_t obase =
                (((size_t)(u * 8 + ou)) * 64 + (v * 8 + ov)) * 2 + rr;
            #pragma unroll
            for (int reg = 0; reg < 4; reg++) {
                const int brw = mt * 16 + lq * 4 + reg;
                if (brw < Bc) {
                    const size_t oidx = obase + (size_t)(b_off + brw) * 8192;
                    if (isbf) ((__hip_bfloat16*)out)[oidx] =
                        __float2bfloat16(acc4[n2][reg]);
                    else ((float*)out)[oidx] = acc4[n2][reg];
                }
            }
        }
    }
}

// ---------------------------------------------------------------------------
extern "C" void kernel_launch(void* const* d_in, const int* in_sizes, int n_in,
                              void* d_out, int out_size, void* d_ws, size_t ws_size,
                              hipStream_t stream)
{
    (void)in_sizes; (void)n_in; (void)out_size;

    const void* in_data = d_in[0];
    const void* filt    = d_in[1];
    const void* bias0   = d_in[2];
    const void* fl[7];
    const void* bl[7];
    for (int l = 1; l <= 6; l++) {
        fl[l] = d_in[1 + 2 * l];
        bl[l] = d_in[2 + 2 * l];
    }
    const void* Wd = d_in[15];

    const int Bfull = 128;
    const size_t perB = (size_t)64 * 64 * 64;

    const size_t wbufBytes  = 565248ull * 16;
    const size_t wdbufBytes = 65536ull * 16;
    const size_t bbufBytes  = 17664ull * 4;
    const size_t headBytes  = 256 + wbufBytes + wdbufBytes + bbufBytes;

    const size_t avail = ws_size > headBytes ? ws_size - headBytes : 0;
    int Bc = 0;
    for (int c = 128; c >= 1; c >>= 1) {
        if ((size_t)2 * c * perB * sizeof(__hip_bfloat16) <= avail) { Bc = c; break; }
    }
    if (Bc == 0) return;

    int* flag = (int*)d_ws;
    ushort_t* wbuf  = (ushort_t*)((char*)d_ws + 256);
    ushort_t* wdbuf = (ushort_t*)((char*)d_ws + 256 + wbufBytes);
    float* bbuf = (float*)((char*)d_ws + 256 + wbufBytes + wdbufBytes);
    __hip_bfloat16* bufA = (__hip_bfloat16*)((char*)d_ws + headBytes);
    __hip_bfloat16* bufB = bufA + (size_t)Bc * perB;

    const int mt4  = (Bc + 63) / 64;
    const int mt16 = (Bc + 15) / 16;

    for (int b_off = 0; b_off < Bfull; b_off += Bc) {
        if (b_off == 0) {
            k_prep0<<<dim3(PREP_BLOCKS + Bc * 64), 256, 0, stream>>>(
                in_data,
                fl[1], fl[2], fl[3], fl[4], fl[5], fl[6], Wd,
                bl[1], bl[2], bl[3], bl[4], bl[5], bl[6],
                wbuf, wdbuf, bbuf, flag,
                filt, bias0, bufA, Bc);
        } else {
            k_stage0<<<dim3(Bc * 64), 256, 0, stream>>>(in_data, filt, bias0, bufA, flag, b_off, Bc);
        }

        // fused L1+L2 (v7): bufA -> bufB
        k_fused12<<<dim3(256 * mt16), 256, 0, stream>>>(
            bufA, wbuf, wbuf + 65536, bbuf, bbuf + 256, bufB, Bc, mt16);

        // level 3: bufB -> bufA  (Nv_out=8, HW=8)
        {
            dim3 grid(4 * 4 * 8 * 8 * mt4);
            k_level4<<<grid, 256, 0, stream>>>(bufB, wbuf + 327680,
                bbuf + 1280, bufA, 8, 8, Bc, mt4);
        }

        // f456: bufA -> out
        k_f456<<<dim3(64 * mt16), 256, 0, stream>>>(bufA,
            wbuf + 1376256, wbuf + 2424832, wbuf + 3473408, wdbuf,
            bbuf + 5376, bbuf + 9472, bbuf + 13568,
            d_out, flag, Bc, b_off, mt16);
    }
}

// Round 15
// 238.770 us; speedup vs baseline: 1.0475x; 1.0475x over previous
//
#include <hip/hip_runtime.h>
#include <hip/hip_bf16.h>
#include <cstdint>
#include <cstddef>

// ButterflyLayer2D on MI355X.
// Round 15 = round 14's v8 resubmitted (container infra failed twice; the
// kernel never ran). Theme: fused12 v8 — fix the so_buf 2x over-allocation.
// Each wave needs 16x68=1088 ushorts of epilogue buffer but the region was
// carved at wave*2176, pushing LDS to 54,272 B — 939 B over the 53.3 KB
// line for 3 blocks/CU. v8: so_buf = base + wave*1088, smem 22784 ushorts
// = 45,568 B -> 3 blocks/CU (12 waves, +50% latency hiding for the
// load->MFMA dependent chains that hold MfmaUtil at 18%). VGPR=80 means
// no register-limit interaction; launch_bounds unchanged (min, not cap).
// Everything else round-13 verbatim.

typedef __attribute__((ext_vector_type(8))) short short8;
typedef __attribute__((ext_vector_type(4))) float f32x4;
typedef unsigned short ushort_t;

static __device__ __forceinline__ float b2f(const __hip_bfloat16 x) {
    return __bfloat162float(x);
}
static __device__ __forceinline__ ushort_t f2bf(float x) {
    __hip_bfloat16 h = __float2bfloat16(x);
    ushort_t u;
    __builtin_memcpy(&u, &h, 2);
    return u;
}
static __device__ __forceinline__ void gl_lds16(const void* g, void* l) {
    __builtin_amdgcn_global_load_lds(
        (const __attribute__((address_space(1))) void*)g,
        (__attribute__((address_space(3))) void*)l, 16, 0, 0);
}
// gfx9 waitcnt encodings: lgkmcnt(0) only / vmcnt(0) only
#define WAIT_LGKM0() __builtin_amdgcn_s_waitcnt(0xC07F)
#define WAIT_VM0()   __builtin_amdgcn_s_waitcnt(0x0F70)

#define PREP_BLOCKS 2533

// ---------------------------------------------------------------------------
// prep work. gid ranges: [0,565248) level weights; [565248,630784) Wd;
// [630784,648448) bias.
// ---------------------------------------------------------------------------
static __device__ __forceinline__ void prep_work(
    int gid, int isbf,
    const void* f1, const void* f2, const void* f3,
    const void* f4, const void* f5, const void* f6, const void* wdsrc,
    const void* b1, const void* b2, const void* b3,
    const void* b4, const void* b5, const void* b6,
    ushort_t* __restrict__ wbuf, ushort_t* __restrict__ wdbuf,
    float* __restrict__ bbuf)
{
    if (gid >= 648448) return;
    if (gid >= 630784) {
        const int bg = gid - 630784;
        const void* src; int base;
        if      (bg <   256) { src = b1; base = 0;     }
        else if (bg <  1280) { src = b2; base = 256;   }
        else if (bg <  5376) { src = b3; base = 1280;  }
        else if (bg <  9472) { src = b4; base = 5376;  }
        else if (bg < 13568) { src = b5; base = 9472;  }
        else                 { src = b6; base = 13568; }
        const int local = bg - base;
        bbuf[bg] = isbf ? b2f(((const __hip_bfloat16*)src)[local])
                        : ((const float*)src)[local];
        return;
    }
    if (gid >= 565248) {
        const int local = gid - 565248;
        const int lane = local & 63;
        const int slot = (local >> 6) & 15;
        const int site = local >> 10;
        const int ks2 = slot >> 3, nh = slot & 7, q = lane >> 4;
        const int n = nh * 16 + (lane & 15);
        const int r = n >> 6, kk = n & 63;
        const int cbase = ks2 * 32 + q * 8;
        ushort_t pk[8];
        if (isbf) {
            const ushort_t* s = (const ushort_t*)wdsrc;
            #pragma unroll
            for (int j = 0; j < 8; j++)
                pk[j] = s[(((size_t)(site * 2 + r) * 64 + cbase + j) * 64) + kk];
        } else {
            const float* s = (const float*)wdsrc;
            #pragma unroll
            for (int j = 0; j < 8; j++)
                pk[j] = f2bf(s[(((size_t)(site * 2 + r) * 64 + cbase + j) * 64) + kk]);
        }
        *(uint4*)&wdbuf[(size_t)local * 8] = *(uint4*)pk;
        return;
    }
    const void* fsrc; int base;
    if      (gid <   8192) { fsrc = f1; base = 0;      }
    else if (gid <  40960) { fsrc = f2; base = 8192;   }
    else if (gid < 172032) { fsrc = f3; base = 40960;  }
    else if (gid < 303104) { fsrc = f4; base = 172032; }
    else if (gid < 434176) { fsrc = f5; base = 303104; }
    else                   { fsrc = f6; base = 434176; }
    const int local = gid - base;
    const int lane = local & 63;
    const int slot = (local >> 6) & 7;
    const int sitetap = local >> 9;
    const int ks = slot >> 2, nh = slot & 3, q = lane >> 4;
    const int n = (lane & 15) + nh * 16;
    const int kbase = ks * 32 + q * 8;
    ushort_t pk[8];
    if (isbf) {
        const ushort_t* s = (const ushort_t*)fsrc + (size_t)sitetap * 4096;
        #pragma unroll
        for (int j = 0; j < 8; j++) pk[j] = s[(kbase + j) * 64 + n];
    } else {
        const float* s = (const float*)fsrc + (size_t)sitetap * 4096;
        #pragma unroll
        for (int j = 0; j < 8; j++) pk[j] = f2bf(s[(kbase + j) * 64 + n]);
    }
    *(uint4*)&wbuf[(size_t)gid * 8] = *(uint4*)pk;
}

// ---------------------------------------------------------------------------
// Stage 0 body: patch-embed, register-tiled, bf16 out.
// Output x0 layout: (h=X, w, b, c) with batch stride Bc (site 0 implicit).
// ---------------------------------------------------------------------------
static __device__ __forceinline__ void stage0_body(
    int blk, int isbf,
    const void* __restrict__ in_data, const void* __restrict__ filt,
    const void* __restrict__ bias, __hip_bfloat16* __restrict__ x0,
    int b_off, int Bc)
{
    const int X  = blk & 63;
    const int bl = blk >> 6;
    const int bg = bl + b_off;

    __shared__ float sIn[4][256];
    __shared__ float sF[16][64];
    __shared__ float sB[64];

    const int t = threadIdx.x;
    const size_t srow = ((size_t)bg * 256 + (size_t)X * 4) * 256;

    if (isbf) {
        const __hip_bfloat16* src = (const __hip_bfloat16*)in_data + srow;
        #pragma unroll
        for (int i = 0; i < 4; i++) {
            int flat = i * 256 + t;
            int p = flat >> 8, col = flat & 255;
            sIn[p][col] = b2f(src[(size_t)p * 256 + col]);
        }
        const __hip_bfloat16* fsrc = (const __hip_bfloat16*)filt;
        #pragma unroll
        for (int i = 0; i < 4; i++) {
            int flat = i * 256 + t;
            sF[flat >> 6][flat & 63] = b2f(fsrc[flat]);
        }
        if (t < 64) sB[t] = b2f(((const __hip_bfloat16*)bias)[t]);
    } else {
        const float* src = (const float*)in_data + srow;
        const int p = t >> 6, c4 = (t & 63) * 4;
        *(float4*)&sIn[p][c4] = *(const float4*)(src + (size_t)p * 256 + c4);
        const float* fsrc = (const float*)filt;
        #pragma unroll
        for (int i = 0; i < 4; i++) {
            int flat = i * 256 + t;
            sF[flat >> 6][flat & 63] = fsrc[flat];
        }
        if (t < 64) sB[t] = ((const float*)bias)[t];
    }
    __syncthreads();

    const int ty = t >> 4;
    const int tc = t & 15;

    float acc[4][4];
    {
        const float4 bv = *(const float4*)&sB[tc * 4];
        #pragma unroll
        for (int yi = 0; yi < 4; yi++) {
            acc[yi][0] = bv.x; acc[yi][1] = bv.y;
            acc[yi][2] = bv.z; acc[yi][3] = bv.w;
        }
    }

    #pragma unroll
    for (int p = 0; p < 4; p++) {
        float4 rin[4], rf[4];
        #pragma unroll
        for (int yi = 0; yi < 4; yi++)
            rin[yi] = *(const float4*)&sIn[p][ty * 16 + yi * 4];
        #pragma unroll
        for (int q = 0; q < 4; q++)
            rf[q] = *(const float4*)&sF[p * 4 + q][tc * 4];
        #pragma unroll
        for (int yi = 0; yi < 4; yi++) {
            #pragma unroll
            for (int q = 0; q < 4; q++) {
                const float a = ((const float*)&rin[yi])[q];
                acc[yi][0] = fmaf(a, rf[q].x, acc[yi][0]);
                acc[yi][1] = fmaf(a, rf[q].y, acc[yi][1]);
                acc[yi][2] = fmaf(a, rf[q].z, acc[yi][2]);
                acc[yi][3] = fmaf(a, rf[q].w, acc[yi][3]);
            }
        }
    }

    // store to (h=X, w, b, c): contiguous 64 B per (w, tc-group)
    ushort_t* dst = (ushort_t*)x0;
    #pragma unroll
    for (int yi = 0; yi < 4; yi++) {
        uint2 pk;
        pk.x = (uint32_t)f2bf(fmaxf(acc[yi][0], 0.f))
             | ((uint32_t)f2bf(fmaxf(acc[yi][1], 0.f)) << 16);
        pk.y = (uint32_t)f2bf(fmaxf(acc[yi][2], 0.f))
             | ((uint32_t)f2bf(fmaxf(acc[yi][3], 0.f)) << 16);
        const int wpos = ty * 4 + yi;
        *(uint2*)(dst + ((size_t)(X * 64 + wpos) * Bc + bl) * 64 + tc * 4) = pk;
    }
}

// ---------------------------------------------------------------------------
// Merged prep + stage0. Grid = PREP_BLOCKS + Bc*64.
// ---------------------------------------------------------------------------
__global__ __launch_bounds__(256) void k_prep0(
    const void* __restrict__ in_data,
    const void* f1, const void* f2, const void* f3,
    const void* f4, const void* f5, const void* f6, const void* wdsrc,
    const void* b1, const void* b2, const void* b3,
    const void* b4, const void* b5, const void* b6,
    ushort_t* __restrict__ wbuf, ushort_t* __restrict__ wdbuf,
    float* __restrict__ bbuf, int* __restrict__ flag,
    const void* __restrict__ filt, const void* __restrict__ bias0,
    __hip_bfloat16* __restrict__ x0, int Bc)
{
    __shared__ int sflag;
    const int t = threadIdx.x;
    if (t < 64) {
        const float v = __uint_as_float(((const uint32_t*)in_data)[t]);
        const bool plaus = (v == 0.0f) || (fabsf(v) > 1e-8f && fabsf(v) < 1e4f);
        const unsigned long long m = __ballot(plaus);
        if (t == 0) sflag = (__popcll(m) >= 48) ? 0 : 1;
    }
    __syncthreads();
    const int isbf = sflag;

    if (blockIdx.x < PREP_BLOCKS) {
        if (blockIdx.x == 0 && t == 0) *flag = isbf;
        prep_work(blockIdx.x * 256 + t, isbf,
                  f1, f2, f3, f4, f5, f6, wdsrc,
                  b1, b2, b3, b4, b5, b6, wbuf, wdbuf, bbuf);
    } else {
        stage0_body(blockIdx.x - PREP_BLOCKS, isbf, in_data, filt, bias0, x0, 0, Bc);
    }
}

__global__ __launch_bounds__(256) void k_stage0(
    const void* __restrict__ in_data, const void* __restrict__ filt,
    const void* __restrict__ bias, __hip_bfloat16* __restrict__ x0,
    const int* __restrict__ flag, int b_off, int Bc)
{
    stage0_body(blockIdx.x, *flag, in_data, filt, bias, x0, b_off, Bc);
}

// ---------------------------------------------------------------------------
// k_fused12 v8: fused levels 1+2, parent-split, pos-innermost MFMA loops.
// Block = (h2 in 16, w2-strip in 4, parent (i,j) in 4, mt16). Grid 256*mt.
// LDS: l1b [0,18432) 16 slices x 16 rows x 72; so_buf [18432,+4352)
// 4 waves x 1088 (FIXED: was 2176/wave, 2x actual need). 45568 B total
// -> 3 blocks/CU (was 2). 1 barrier.
// ---------------------------------------------------------------------------
__global__ __launch_bounds__(256, 2) void k_fused12(
    const __hip_bfloat16* __restrict__ xin,   // L0: (64,64,Bc,64) pos-major
    const ushort_t* __restrict__ w1,          // lvl1 B-frags (4 sites)
    const ushort_t* __restrict__ w2,          // lvl2 B-frags (16 sites)
    const float* __restrict__ b1, const float* __restrict__ b2,
    __hip_bfloat16* __restrict__ xout,        // L2 out: (16,16,16,Bc,64)
    int Bc, int mtiles)
{
    __shared__ __align__(16) ushort_t smem[22784];  // l1b 18432 + so_buf 4352

    int idx = blockIdx.x;
    const int mt = idx % mtiles; idx /= mtiles;
    const int parent = idx & 3; idx >>= 2;
    const int wstrip = idx & 3;
    const int h2p = idx >> 2;
    const int ip = parent >> 1, jp = parent & 1;

    const int t = threadIdx.x;
    const int wave = t >> 6, lane = t & 63;
    const int lm = lane & 15, lq = lane >> 4;

    const size_t pstride = (size_t)Bc * 64;

    int brow = mt * 16 + lm;
    if (brow >= Bc) brow = Bc - 1;

    const ushort_t* w1site = w1 + (size_t)parent * 16384 + lane * 8;

    float bv1[4];
    #pragma unroll
    for (int fn = 0; fn < 4; fn++) bv1[fn] = b1[parent * 64 + fn * 16 + lm];

    const f32x4 zero = {0.f, 0.f, 0.f, 0.f};
    ushort_t* l1b = smem;                    // 16 slices x 1152
    const int wa = wave >> 1, wb = wave & 1; // phase-A ab position

    // ---------------- phase A: pos-innermost, barrier-free ----------------
    {
        f32x4 acc[4][4];   // [pos][fn]
        #pragma unroll
        for (int p = 0; p < 4; p++)
            #pragma unroll
            for (int fn = 0; fn < 4; fn++) acc[p][fn] = zero;

        #pragma unroll
        for (int cd = 0; cd < 4; cd++) {
            const int hi0 = 4 * h2p + 2 * wa + (cd >> 1);
            const int wbase = 2 * wb + (cd & 1);
            #pragma unroll
            for (int ks = 0; ks < 2; ks++) {
                short8 afr[4];
                #pragma unroll
                for (int pos = 0; pos < 4; pos++) {
                    const int wi0 = 4 * (wstrip * 4 + pos) + wbase;
                    afr[pos] = *(const short8*)(
                        xin + ((size_t)hi0 * 64 + wi0) * pstride
                            + (size_t)brow * 64 + ks * 32 + lq * 8);
                }
                #pragma unroll
                for (int fn = 0; fn < 4; fn++) {
                    short8 bfr = *(const short8*)(w1site + (cd * 8 + ks * 4 + fn) * 512);
                    #pragma unroll
                    for (int pos = 0; pos < 4; pos++)
                        acc[pos][fn] = __builtin_amdgcn_mfma_f32_16x16x32_bf16(
                            afr[pos], bfr, acc[pos][fn], 0, 0, 0);
                }
            }
        }
        // epilogue -> L1 slices (pos*4 + wave), bias1 + relu
        #pragma unroll
        for (int pos = 0; pos < 4; pos++) {
            ushort_t* dst = l1b + (pos * 4 + wave) * 1152;
            #pragma unroll
            for (int fn = 0; fn < 4; fn++) {
                #pragma unroll
                for (int r = 0; r < 4; r++) {
                    const int m = lq * 4 + r;
                    dst[m * 72 + fn * 16 + lm] =
                        f2bf(fmaxf(acc[pos][fn][r] + bv1[fn], 0.f));
                }
            }
        }
    }
    __syncthreads();   // the ONLY barrier: all L1 slices visible cross-wave

    // ---------------- phase B: wave = child site, pos-innermost -----------
    {
        const int di = wave >> 1, dj = wave & 1;
        const int s2 = (2 * ip + di) * 4 + (2 * jp + dj);
        const ushort_t* w2site = w2 + (size_t)s2 * 16384 + lane * 8;

        float bv2[4];
        #pragma unroll
        for (int fn = 0; fn < 4; fn++) bv2[fn] = b2[s2 * 64 + fn * 16 + lm];

        f32x4 acc[4][4];   // [pos][fn]
        #pragma unroll
        for (int p = 0; p < 4; p++)
            #pragma unroll
            for (int fn = 0; fn < 4; fn++) acc[p][fn] = zero;

        #pragma unroll
        for (int ab = 0; ab < 4; ab++) {
            #pragma unroll
            for (int ks = 0; ks < 2; ks++) {
                short8 afr[4];
                #pragma unroll
                for (int pos = 0; pos < 4; pos++) {
                    const ushort_t* sl = l1b + (pos * 4 + ab) * 1152;
                    afr[pos] = *(const short8*)&sl[lm * 72 + ks * 32 + lq * 8];
                }
                #pragma unroll
                for (int fn = 0; fn < 4; fn++) {
                    short8 bfr = *(const short8*)(w2site + (ab * 8 + ks * 4 + fn) * 512);
                    #pragma unroll
                    for (int pos = 0; pos < 4; pos++)
                        acc[pos][fn] = __builtin_amdgcn_mfma_f32_16x16x32_bf16(
                            afr[pos], bfr, acc[pos][fn], 0, 0, 0);
                }
            }
        }

        // epilogue per position: LDS transpose + coalesced uint4 stores
        ushort_t* so_buf = smem + 18432 + wave * 1088;
        #pragma unroll
        for (int pos = 0; pos < 4; pos++) {
            const int w2p = wstrip * 4 + pos;
            #pragma unroll
            for (int fn = 0; fn < 4; fn++) {
                #pragma unroll
                for (int r = 0; r < 4; r++) {
                    const int m = lq * 4 + r;
                    so_buf[m * 68 + fn * 16 + lm] =
                        f2bf(fmaxf(acc[pos][fn][r] + bv2[fn], 0.f));
                }
            }
            const size_t obase = ((size_t)s2 * 256 + h2p * 16 + w2p) * pstride;
            #pragma unroll
            for (int i2 = 0; i2 < 2; i2++) {
                const int task = i2 * 64 + lane;
                const int oct = task & 7, row = task >> 3;
                const int brw = mt * 16 + row;
                if (brw < Bc) {
                    *(uint4*)(xout + obase + (size_t)brw * 64 + oct * 8) =
                        *(const uint4*)&so_buf[row * 68 + oct * 8];
                }
            }
        }
    }
}

// ---------------------------------------------------------------------------
// Repeat level (used for lvl3 only), round-13 verbatim.
// ---------------------------------------------------------------------------
__global__ __launch_bounds__(256, 2) void k_level4(
    const __hip_bfloat16* __restrict__ xin,
    const ushort_t* __restrict__ wbuf,
    const float* __restrict__ bbuf,
    __hip_bfloat16* __restrict__ xout,
    int Nv_out, int HW, int Bc, int mtiles)
{
    __shared__ __align__(16) ushort_t smem[17408];

    int idx = blockIdx.x;
    const int mt = idx % mtiles; idx /= mtiles;
    const int w  = idx % HW; idx /= HW;
    const int h  = idx % HW; idx /= HW;
    const int Nv_in = Nv_out >> 1;
    const int vp = idx % Nv_in;
    const int up = idx / Nv_in;

    const int t = threadIdx.x;
    const int wave = t >> 6, lane = t & 63;
    const int lm = lane & 15, lq = lane >> 4;

    const int so = (2 * up + (wave >> 1)) * Nv_out + (2 * vp + (wave & 1));
    const int H_in = HW * 2;
    const size_t pstride = (size_t)Bc * 64;
    const size_t siteb = (size_t)(up * Nv_in + vp) * H_in * H_in * pstride;
    const ushort_t* wsite = wbuf + (size_t)so * 4 * 4096 + lane * 8;

    {
        const int hi = 2 * h + (wave >> 1), wi = 2 * w + (wave & 1);
        const size_t tapoff = siteb + ((size_t)hi * H_in + wi) * pstride;
        #pragma unroll
        for (int j = 0; j < 8; j++) {
            const int ks = j >> 2, mh = j & 3;
            int b = mt * 64 + mh * 16 + lm;
            if (b >= Bc) b = Bc - 1;
            gl_lds16(xin + tapoff + (size_t)b * 64 + ks * 32 + lq * 8,
                     &smem[(wave * 8 + j) * 512]);
        }
    }

    short8 breg[32];
    #pragma unroll
    for (int s = 0; s < 32; s++)
        breg[s] = *(const short8*)(wsite + s * 512);
    __builtin_amdgcn_sched_barrier(0);

    float bv[4];
    #pragma unroll
    for (int fn = 0; fn < 4; fn++) bv[fn] = bbuf[so * 64 + fn * 16 + lm];

    __syncthreads();

    const f32x4 zero = {0.f, 0.f, 0.f, 0.f};
    f32x4 acc[4][4];
    #pragma unroll
    for (int i = 0; i < 4; i++)
        #pragma unroll
        for (int j = 0; j < 4; j++) acc[i][j] = zero;

    #pragma unroll
    for (int tap = 0; tap < 4; tap++) {
        #pragma unroll
        for (int ks = 0; ks < 2; ks++) {
            #pragma unroll
            for (int fm = 0; fm < 4; fm++) {
                short8 a = *(const short8*)&smem[(tap * 8 + ks * 4 + fm) * 512 + lane * 8];
                #pragma unroll
                for (int fn = 0; fn < 4; fn++)
                    acc[fm][fn] = __builtin_amdgcn_mfma_f32_16x16x32_bf16(
                        a, breg[tap * 8 + ks * 4 + fn], acc[fm][fn], 0, 0, 0);
            }
        }
    }
    __syncthreads();

    ushort_t* so_buf = smem + wave * 4352;
    #pragma unroll
    for (int fm = 0; fm < 4; fm++) {
        #pragma unroll
        for (int fn = 0; fn < 4; fn++) {
            #pragma unroll
            for (int r = 0; r < 4; r++) {
                const int row = fm * 16 + lq * 4 + r;
                so_buf[row * 68 + fn * 16 + lm] =
                    f2bf(fmaxf(acc[fm][fn][r] + bv[fn], 0.f));
            }
        }
    }
    __syncthreads();

    const size_t obase = ((size_t)so * HW * HW + (size_t)h * HW + w) * pstride;
    #pragma unroll
    for (int i = 0; i < 8; i++) {
        const int task = i * 64 + lane;
        const int oct = task & 7, row = task >> 3;
        const int b = mt * 64 + row;
        if (b < Bc) {
            *(uint4*)(xout + obase + (size_t)b * 64 + oct * 8) =
                *(const uint4*)&so_buf[row * 68 + oct * 8];
        }
    }
}

// ---------------------------------------------------------------------------
// k_f456: fused L4 + L5 + L6 + final (round-13 verbatim).
// ---------------------------------------------------------------------------
__global__ __launch_bounds__(256) void k_f456(
    const __hip_bfloat16* __restrict__ xin,   // L3 out: (64, 8,8, Bc, 64)
    const ushort_t* __restrict__ w4, const ushort_t* __restrict__ w5,
    const ushort_t* __restrict__ w6, const ushort_t* __restrict__ wd,
    const float* __restrict__ b4, const float* __restrict__ b5,
    const float* __restrict__ b6,
    void* __restrict__ out, const int* __restrict__ flag,
    int Bc, int b_off, int mtiles)
{
    const int isbf = *flag;
    const int bx = blockIdx.x;
    const int mt = bx % mtiles;
    const int site = bx / mtiles;
    const int u = site >> 3, v = site & 7;

    __shared__ __align__(16) ushort_t smem[37376];

    const int t = threadIdx.x;
    const int wv = t >> 6, lane = t & 63;
    const int lm = lane & 15, lq = lane >> 4;

    const ushort_t* w6s = w6 + (size_t)site * 16384 + lane * 8;
    const ushort_t* wds = wd + (size_t)site * 8192  + lane * 8;

    float bv4[4], bv5[4];
    #pragma unroll
    for (int fn = 0; fn < 4; fn++) {
        bv4[fn] = b4[site * 64 + fn * 16 + lm];
        bv5[fn] = b5[site * 64 + fn * 16 + lm];
    }
    const float bv6 = b6[site * 64 + wv * 16 + lm];

    {
        const ushort_t* w4s = w4 + (size_t)site * 16384;
        #pragma unroll
        for (int s2 = 0; s2 < 8; s2++) {
            const int s = wv * 8 + s2;
            gl_lds16(w4s + s * 512 + lane * 8, &smem[s * 512]);
        }
    }
    __syncthreads();

    const f32x4 zero = {0.f, 0.f, 0.f, 0.f};
    const int h5 = wv >> 1, w5p = wv & 1;
    ushort_t* mid1w = smem + 16384 + wv * 4224;
    ushort_t* Aw = smem + 33280 + wv * 1024;
    const size_t pstride = (size_t)Bc * 64;

    int brow = mt * 16 + lm;
    if (brow >= Bc) brow = Bc - 1;
    const __hip_bfloat16* xbase =
        xin + (size_t)site * 64 * pstride + (size_t)brow * 64 + lq * 8;

    for (int i = 0; i < 4; i++) {
        const int h4 = 2 * h5 + (i >> 1), w4p = 2 * w5p + (i & 1);
        f32x4 acc[4];
        #pragma unroll
        for (int b_ = 0; b_ < 4; b_++) acc[b_] = zero;

        for (int tap = 0; tap < 4; tap++) {
            const int h3 = 2 * h4 + (tap >> 1), w3 = 2 * w4p + (tap & 1);
            const size_t poff = (size_t)(h3 * 8 + w3) * pstride;
            WAIT_LGKM0();
            #pragma unroll
            for (int ks = 0; ks < 2; ks++) {
                gl_lds16(xbase + poff + ks * 32, &Aw[ks * 512]);
            }
            WAIT_VM0();
            __builtin_amdgcn_sched_barrier(0);
            #pragma unroll
            for (int ks = 0; ks < 2; ks++) {
                short8 a = *(const short8*)&Aw[ks * 512 + lane * 8];
                #pragma unroll
                for (int fn = 0; fn < 4; fn++) {
                    short8 bfr = *(const short8*)&smem[(tap * 8 + ks * 4 + fn) * 512 + lane * 8];
                    acc[fn] = __builtin_amdgcn_mfma_f32_16x16x32_bf16(a, bfr, acc[fn], 0, 0, 0);
                }
            }
        }
        #pragma unroll
        for (int fn = 0; fn < 4; fn++) {
            #pragma unroll
            for (int r = 0; r < 4; r++) {
                const int m = lq * 4 + r;
                const int ch = fn * 16 + lm;
                mid1w[m * 264 + i * 64 + ch] =
                    f2bf(fmaxf(acc[fn][r] + bv4[fn], 0.f));
            }
        }
    }
    __syncthreads();

    {
        const ushort_t* w5s = w5 + (size_t)site * 16384;
        #pragma unroll
        for (int s2 = 0; s2 < 8; s2++) {
            const int s = wv * 8 + s2;
            gl_lds16(w5s + s * 512 + lane * 8, &smem[s * 512]);
        }
    }
    __syncthreads();

    short8 b3r[8];
    short8 wdr[4];
    {
        f32x4 acc2[4];
        #pragma unroll
        for (int b_ = 0; b_ < 4; b_++) acc2[b_] = zero;

        #pragma unroll
        for (int i = 0; i < 4; i++) {
            #pragma unroll
            for (int ks = 0; ks < 2; ks++) {
                short8 a0 = *(const short8*)&mid1w[lm * 264 + i * 64 + ks * 32 + lq * 8];
                #pragma unroll
                for (int fn = 0; fn < 4; fn++) {
                    short8 bfr = *(const short8*)&smem[(i * 8 + ks * 4 + fn) * 512 + lane * 8];
                    acc2[fn] = __builtin_amdgcn_mfma_f32_16x16x32_bf16(a0, bfr, acc2[fn], 0, 0, 0);
                }
            }
        }

        #pragma unroll
        for (int tap = 0; tap < 4; tap++)
            #pragma unroll
            for (int ks = 0; ks < 2; ks++)
                b3r[tap * 2 + ks] = *(const short8*)(w6s + (tap * 8 + ks * 4 + wv) * 512);
        #pragma unroll
        for (int ks = 0; ks < 2; ks++)
            #pragma unroll
            for (int n2 = 0; n2 < 2; n2++)
                wdr[ks * 2 + n2] = *(const short8*)(wds + (ks * 8 + 2 * wv + n2) * 512);

        #pragma unroll
        for (int fn = 0; fn < 4; fn++) {
            #pragma unroll
            for (int r = 0; r < 4; r++) {
                const int m = lq * 4 + r;
                const int ch = fn * 16 + lm;
                mid1w[m * 72 + ch] =
                    f2bf(fmaxf(acc2[fn][r] + bv5[fn], 0.f));
            }
        }
    }
    __syncthreads();

    {
        f32x4 acc3 = zero;
        #pragma unroll
        for (int tap = 0; tap < 4; tap++) {
            const ushort_t* sl = smem + 16384 + tap * 4224;
            #pragma unroll
            for (int ks = 0; ks < 2; ks++) {
                short8 a0 = *(const short8*)&sl[lm * 72 + ks * 32 + lq * 8];
                acc3 = __builtin_amdgcn_mfma_f32_16x16x32_bf16(a0, b3r[tap * 2 + ks], acc3, 0, 0, 0);
            }
        }
        ushort_t* mid3 = smem + 33280;
        #pragma unroll
        for (int r = 0; r < 4; r++) {
            const int m = lq * 4 + r;
            const int ch = wv * 16 + lm;
            mid3[m * 72 + ch] = f2bf(fmaxf(acc3[r] + bv6, 0.f));
        }
    }
    __syncthreads();

    {
        const ushort_t* mid3 = smem + 33280;
        f32x4 acc4[2];
        acc4[0] = zero; acc4[1] = zero;
        #pragma unroll
        for (int ks = 0; ks < 2; ks++) {
            short8 a0 = *(const short8*)&mid3[lm * 72 + ks * 32 + lq * 8];
            #pragma unroll
            for (int n2 = 0; n2 < 2; n2++) {
                acc4[n2] = __builtin_amdgcn_mfma_f32_16x16x32_bf16(a0, wdr[ks * 2 + n2], acc4[n2], 0, 0, 0);
            }
        }
        #pragma unroll
        for (int n2 = 0; n2 < 2; n2++) {
            const int n = (2 * wv + n2) * 16 + lm;
            const int rr = n >> 6, ou = (n >> 3) & 7, ov = n & 7;
            const size_t obase =
                (((size_t)(u * 8 + ou)) * 64 + (v * 8 + ov)) * 2 + rr;
            #pragma unroll
            for (int reg = 0; reg < 4; reg++) {
                const int brw = mt * 16 + lq * 4 + reg;
                if (brw < Bc) {
                    const size_t oidx = obase + (size_t)(b_off + brw) * 8192;
                    if (isbf) ((__hip_bfloat16*)out)[oidx] =
                        __float2bfloat16(acc4[n2][reg]);
                    else ((float*)out)[oidx] = acc4[n2][reg];
                }
            }
        }
    }
}

// ---------------------------------------------------------------------------
extern "C" void kernel_launch(void* const* d_in, const int* in_sizes, int n_in,
                              void* d_out, int out_size, void* d_ws, size_t ws_size,
                              hipStream_t stream)
{
    (void)in_sizes; (void)n_in; (void)out_size;

    const void* in_data = d_in[0];
    const void* filt    = d_in[1];
    const void* bias0   = d_in[2];
    const void* fl[7];
    const void* bl[7];
    for (int l = 1; l <= 6; l++) {
        fl[l] = d_in[1 + 2 * l];
        bl[l] = d_in[2 + 2 * l];
    }
    const void* Wd = d_in[15];

    const int Bfull = 128;
    const size_t perB = (size_t)64 * 64 * 64;

    const size_t wbufBytes  = 565248ull * 16;
    const size_t wdbufBytes = 65536ull * 16;
    const size_t bbufBytes  = 17664ull * 4;
    const size_t headBytes  = 256 + wbufBytes + wdbufBytes + bbufBytes;

    const size_t avail = ws_size > headBytes ? ws_size - headBytes : 0;
    int Bc = 0;
    for (int c = 128; c >= 1; c >>= 1) {
        if ((size_t)2 * c * perB * sizeof(__hip_bfloat16) <= avail) { Bc = c; break; }
    }
    if (Bc == 0) return;

    int* flag = (int*)d_ws;
    ushort_t* wbuf  = (ushort_t*)((char*)d_ws + 256);
    ushort_t* wdbuf = (ushort_t*)((char*)d_ws + 256 + wbufBytes);
    float* bbuf = (float*)((char*)d_ws + 256 + wbufBytes + wdbufBytes);
    __hip_bfloat16* bufA = (__hip_bfloat16*)((char*)d_ws + headBytes);
    __hip_bfloat16* bufB = bufA + (size_t)Bc * perB;

    const int mt4  = (Bc + 63) / 64;
    const int mt16 = (Bc + 15) / 16;

    for (int b_off = 0; b_off < Bfull; b_off += Bc) {
        if (b_off == 0) {
            k_prep0<<<dim3(PREP_BLOCKS + Bc * 64), 256, 0, stream>>>(
                in_data,
                fl[1], fl[2], fl[3], fl[4], fl[5], fl[6], Wd,
                bl[1], bl[2], bl[3], bl[4], bl[5], bl[6],
                wbuf, wdbuf, bbuf, flag,
                filt, bias0, bufA, Bc);
        } else {
            k_stage0<<<dim3(Bc * 64), 256, 0, stream>>>(in_data, filt, bias0, bufA, flag, b_off, Bc);
        }

        // fused L1+L2 (v8): bufA -> bufB
        k_fused12<<<dim3(256 * mt16), 256, 0, stream>>>(
            bufA, wbuf, wbuf + 65536, bbuf, bbuf + 256, bufB, Bc, mt16);

        // level 3: bufB -> bufA  (Nv_out=8, HW=8)
        {
            dim3 grid(4 * 4 * 8 * 8 * mt4);
            k_level4<<<grid, 256, 0, stream>>>(bufB, wbuf + 327680,
                bbuf + 1280, bufA, 8, 8, Bc, mt4);
        }

        // f456: bufA -> out
        k_f456<<<dim3(64 * mt16), 256, 0, stream>>>(bufA,
            wbuf + 1376256, wbuf + 2424832, wbuf + 3473408, wdbuf,
            bbuf + 5376, bbuf + 9472, bbuf + 13568,
            d_out, flag, Bc, b_off, mt16);
    }
}